// Round 8
// baseline (121.043 us; speedup 1.0000x reference)
//
#include <hip/hip_runtime.h>
#include <math.h>

#define NN 768
#define CC 256
#define TI 3     // rows per block (both kernels)
#define JC 256   // j columns per k_attn block
#define NJC 3    // j chunks: 3 * 256 = 768

typedef __attribute__((ext_vector_type(4))) float v4f;

__device__ __forceinline__ float leaky(float x) { return x >= 0.0f ? x : 0.2f * x; }

__device__ __forceinline__ float waveMax(float v) {
    #pragma unroll
    for (int o = 32; o > 0; o >>= 1) v = fmaxf(v, __shfl_xor(v, o, 64));
    return v;
}
__device__ __forceinline__ float waveSum(float v) {
    #pragma unroll
    for (int o = 32; o > 0; o >>= 1) v += __shfl_xor(v, o, 64);
    return v;
}

// Kernel 1 (unchanged): f = features @ FC; g[c][j] = w1*f[j][c]+b;
// D0/D1 = per-row linear-term dots; ut4[triple][c] = {w0*f_r0[c], w0*f_r1[c],
// w0*f_r2[c], 0.4*lin_w[c]} — read by k_attn via s_load (scalar pipe).
__global__ __launch_bounds__(768) void k_prep(
    const float* __restrict__ features,
    const float* __restrict__ FC,
    const float* __restrict__ fc_w,
    const float* __restrict__ fc_b,
    const float* __restrict__ lin_w,
    float* __restrict__ f,
    float* __restrict__ g,
    float* __restrict__ D0,
    float* __restrict__ D1,
    float4* __restrict__ ut4)
{
    __shared__ float sA[TI * CC];
    __shared__ float sF[TI * CC];
    __shared__ float sredD[12], sredW[12];

    const int t  = threadIdx.x;
    const int r  = t >> 8;
    const int c  = t & 255;
    const int i0 = blockIdx.x * TI;

    sA[r * CC + c] = features[(i0 + r) * CC + c];
    __syncthreads();

    float a = 0.f;
    const float* fcp = FC + c;
    const float* ap  = sA + r * CC;
    #pragma unroll 8
    for (int k = 0; k < CC; ++k)
        a = fmaf(ap[k], fcp[k * CC], a);

    const float w1 = fc_w[1], b = fc_b[0];
    f[(i0 + r) * CC + c] = a;
    g[c * NN + i0 + r]   = fmaf(w1, a, b);
    sF[r * CC + c] = a;

    const float lw = lin_w[c];
    float dv = waveSum(lw * a);
    float wv = waveSum(lw);
    const int wid = t >> 6;
    if ((t & 63) == 0) { sredD[wid] = dv; sredW[wid] = wv; }
    __syncthreads();
    if (t < TI) {
        float D = sredD[t*4] + sredD[t*4+1] + sredD[t*4+2] + sredD[t*4+3];
        float W = sredW[t*4] + sredW[t*4+1] + sredW[t*4+2] + sredW[t*4+3];
        D0[i0 + t] = fc_w[0] * D;
        D1[i0 + t] = fmaf(w1, D, b * W);
    }
    if (t < CC) {
        const float w0 = fc_w[0];
        ut4[blockIdx.x * CC + t] = make_float4(w0 * sF[t],
                                               w0 * sF[CC + t],
                                               w0 * sF[2*CC + t],
                                               0.4f * lin_w[t]);
    }
}

// Kernel 2: 768 blocks x 256 threads. Block = (row-triple it, j-chunk jc).
// Phase 1's u operand is loaded with EXPLICIT s_load_dwordx4 inline asm:
// a wave-uniform vector load would return a replicated 1KB/wave through the
// TCP — that return-bus saturation was the invariant ~25 us across rounds 5-7.
__global__ __launch_bounds__(256) void k_attn(
    const float* __restrict__ f,      // [N][C]
    const float* __restrict__ g,      // [C][N]
    const float4* __restrict__ ut4,   // [N/3][C]
    const float* __restrict__ D0,     // [N]
    const float* __restrict__ D1,     // [N]
    const float* __restrict__ coords, // [N][3]
    const float* __restrict__ sc_w,
    const float* __restrict__ sc_b,
    const float* __restrict__ lin_w,  // [C+3]
    const float* __restrict__ lin_b,
    float* __restrict__ hp,           // [NJC][N][C] partial sums
    float* __restrict__ Mp,           // [N][NJC] partial max
    float* __restrict__ Lp)           // [N][NJC] partial expsum
{
    __shared__ float4 pp[JC];           // 4 KB: {e0,e1,e2,-} per block-local j
    __shared__ float  hpart[4][TI][CC]; // 12 KB: per-wave h partials
    __shared__ float4 sredm4[4];
    __shared__ float4 sreds4[4];

    const int t    = threadIdx.x;
    const int it   = blockIdx.x & 255;  // row-triple
    const int jc   = blockIdx.x >> 8;   // j-chunk 0..2
    const int i0   = it * TI;
    const int jb   = jc * JC;
    const int j    = jb + t;
    const int w    = t >> 6;
    const int lane = t & 63;

    // ---- Phase 1: 0.4*wc*|u_r + g_j| over c; u via TRUE scalar loads ----
    float a0 = 0.f, a1 = 0.f, a2 = 0.f;
    const float* upg = (const float*)(ut4 + (size_t)it * CC);  // uniform -> SGPR pair
    const float* gp  = g + j;

    for (int cg = 0; cg < CC; cg += 8) {
        v4f u0, u1, u2, u3, u4, u5, u6, u7;
        asm volatile("s_load_dwordx4 %0, %1, 0"   : "=s"(u0) : "s"(upg));
        asm volatile("s_load_dwordx4 %0, %1, 16"  : "=s"(u1) : "s"(upg));
        asm volatile("s_load_dwordx4 %0, %1, 32"  : "=s"(u2) : "s"(upg));
        asm volatile("s_load_dwordx4 %0, %1, 48"  : "=s"(u3) : "s"(upg));
        asm volatile("s_load_dwordx4 %0, %1, 64"  : "=s"(u4) : "s"(upg));
        asm volatile("s_load_dwordx4 %0, %1, 80"  : "=s"(u5) : "s"(upg));
        asm volatile("s_load_dwordx4 %0, %1, 96"  : "=s"(u6) : "s"(upg));
        asm volatile("s_load_dwordx4 %0, %1, 112" : "=s"(u7) : "s"(upg));

        // vector g loads overlap the SMEM latency
        float gj0 = gp[(cg+0) * NN];
        float gj1 = gp[(cg+1) * NN];
        float gj2 = gp[(cg+2) * NN];
        float gj3 = gp[(cg+3) * NN];
        float gj4 = gp[(cg+4) * NN];
        float gj5 = gp[(cg+5) * NN];
        float gj6 = gp[(cg+6) * NN];
        float gj7 = gp[(cg+7) * NN];

        // SMEM returns out-of-order -> full lgkm wait; tie quads so uses
        // can't be scheduled above the wait.
        asm volatile("s_waitcnt lgkmcnt(0)"
                     : "+s"(u0), "+s"(u1), "+s"(u2), "+s"(u3),
                       "+s"(u4), "+s"(u5), "+s"(u6), "+s"(u7));

        a0 = fmaf(u0.w, fabsf(u0.x + gj0), a0);
        a1 = fmaf(u0.w, fabsf(u0.y + gj0), a1);
        a2 = fmaf(u0.w, fabsf(u0.z + gj0), a2);
        a0 = fmaf(u1.w, fabsf(u1.x + gj1), a0);
        a1 = fmaf(u1.w, fabsf(u1.y + gj1), a1);
        a2 = fmaf(u1.w, fabsf(u1.z + gj1), a2);
        a0 = fmaf(u2.w, fabsf(u2.x + gj2), a0);
        a1 = fmaf(u2.w, fabsf(u2.y + gj2), a1);
        a2 = fmaf(u2.w, fabsf(u2.z + gj2), a2);
        a0 = fmaf(u3.w, fabsf(u3.x + gj3), a0);
        a1 = fmaf(u3.w, fabsf(u3.y + gj3), a1);
        a2 = fmaf(u3.w, fabsf(u3.z + gj3), a2);
        a0 = fmaf(u4.w, fabsf(u4.x + gj4), a0);
        a1 = fmaf(u4.w, fabsf(u4.y + gj4), a1);
        a2 = fmaf(u4.w, fabsf(u4.z + gj4), a2);
        a0 = fmaf(u5.w, fabsf(u5.x + gj5), a0);
        a1 = fmaf(u5.w, fabsf(u5.y + gj5), a1);
        a2 = fmaf(u5.w, fabsf(u5.z + gj5), a2);
        a0 = fmaf(u6.w, fabsf(u6.x + gj6), a0);
        a1 = fmaf(u6.w, fabsf(u6.y + gj6), a1);
        a2 = fmaf(u6.w, fabsf(u6.z + gj6), a2);
        a0 = fmaf(u7.w, fabsf(u7.x + gj7), a0);
        a1 = fmaf(u7.w, fabsf(u7.y + gj7), a1);
        a2 = fmaf(u7.w, fabsf(u7.z + gj7), a2);

        upg += 32;   // 8 c * 4 floats, stays uniform/SGPR
    }

    // coord part + 0.6-linear part + outer leaky
    const float sw0 = sc_w[0], sw1 = sc_w[1], sb = sc_b[0], lb = lin_b[0];
    const float lw30 = lin_w[CC], lw31 = lin_w[CC+1], lw32 = lin_w[CC+2];
    const float cj0 = fmaf(sw1, coords[j*3+0], sb);
    const float cj1 = fmaf(sw1, coords[j*3+1], sb);
    const float cj2 = fmaf(sw1, coords[j*3+2], sb);
    const float d1  = D1[j];
    float accs[3] = {a0, a1, a2};
    float scv[3];
    #pragma unroll
    for (int rr = 0; rr < TI; ++rr) {
        const int i = i0 + rr;
        float sd = lw30 * leaky(fmaf(sw0, coords[i*3+0], cj0))
                 + lw31 * leaky(fmaf(sw0, coords[i*3+1], cj1))
                 + lw32 * leaky(fmaf(sw0, coords[i*3+2], cj2));
        scv[rr] = leaky(accs[rr] + sd + 0.6f * (D0[i] + d1) + lb);
    }

    // ---- Phase 2: partial softmax over this block's 256 j ----
    {
        float v0 = waveMax(scv[0]);
        float v1 = waveMax(scv[1]);
        float v2 = waveMax(scv[2]);
        if (lane == 0) sredm4[w] = make_float4(v0, v1, v2, 0.f);
    }
    __syncthreads();
    float m[TI];
    {
        float4 x0 = sredm4[0], x1 = sredm4[1], x2 = sredm4[2], x3 = sredm4[3];
        m[0] = fmaxf(fmaxf(x0.x, x1.x), fmaxf(x2.x, x3.x));
        m[1] = fmaxf(fmaxf(x0.y, x1.y), fmaxf(x2.y, x3.y));
        m[2] = fmaxf(fmaxf(x0.z, x1.z), fmaxf(x2.z, x3.z));
    }
    float e0 = __expf(scv[0] - m[0]);
    float e1 = __expf(scv[1] - m[1]);
    float e2 = __expf(scv[2] - m[2]);
    pp[t] = make_float4(e0, e1, e2, 0.f);
    {
        float v0 = waveSum(e0);
        float v1 = waveSum(e1);
        float v2 = waveSum(e2);
        if (lane == 0) sreds4[w] = make_float4(v0, v1, v2, 0.f);
    }
    __syncthreads();   // publishes pp + sreds4
    if (t < TI) {
        float4 s0 = sreds4[0], s1 = sreds4[1], s2 = sreds4[2], s3 = sreds4[3];
        float l = (t == 0) ? (s0.x + s1.x + s2.x + s3.x)
                : (t == 1) ? (s0.y + s1.y + s2.y + s3.y)
                           : (s0.z + s1.z + s2.z + s3.z);
        float mm = (t == 0) ? m[0] : (t == 1) ? m[1] : m[2];
        Mp[(i0 + t) * NJC + jc] = mm;
        Lp[(i0 + t) * NJC + jc] = l;
    }

    // ---- Phase 3: wave w owns j-slice [64w,64w+64); lane owns 4 channels ----
    float4 h0 = make_float4(0.f,0.f,0.f,0.f);
    float4 h1 = h0, h2 = h0;
    const float4* f4 = (const float4*)f;   // [N][64] float4
    const int jsl = w * 64;
    #pragma unroll 4
    for (int jx = 0; jx < 64; ++jx) {
        const int jl = jsl + jx;
        float4 fv = f4[(size_t)(jb + jl) * 64 + lane];  // coalesced 1KB/wave
        float4 e  = pp[jl];                              // ds_read_b128 broadcast
        h0.x = fmaf(e.x, fv.x, h0.x); h0.y = fmaf(e.x, fv.y, h0.y);
        h0.z = fmaf(e.x, fv.z, h0.z); h0.w = fmaf(e.x, fv.w, h0.w);
        h1.x = fmaf(e.y, fv.x, h1.x); h1.y = fmaf(e.y, fv.y, h1.y);
        h1.z = fmaf(e.y, fv.z, h1.z); h1.w = fmaf(e.y, fv.w, h1.w);
        h2.x = fmaf(e.z, fv.x, h2.x); h2.y = fmaf(e.z, fv.y, h2.y);
        h2.z = fmaf(e.z, fv.z, h2.z); h2.w = fmaf(e.z, fv.w, h2.w);
    }
    *(float4*)&hpart[w][0][4*lane] = h0;
    *(float4*)&hpart[w][1][4*lane] = h1;
    *(float4*)&hpart[w][2][4*lane] = h2;
    __syncthreads();

    // ---- Reduce the 4 wave-partials per row; store hp ----
    #pragma unroll
    for (int r = 0; r < TI; ++r) {
        float h = hpart[0][r][t] + hpart[1][r][t] + hpart[2][r][t] + hpart[3][r][t];
        hp[((size_t)jc * NN + i0 + r) * CC + t] = h;
    }
}

// Kernel 3: combine the 3 j-chunk partials per row, normalize, elu.
__global__ __launch_bounds__(256) void k_comb(
    const float* __restrict__ hp,
    const float* __restrict__ Mp,
    const float* __restrict__ Lp,
    float* __restrict__ out)
{
    const int t = threadIdx.x;
    const int i = blockIdx.x;

    float m0 = Mp[i*NJC+0], m1 = Mp[i*NJC+1], m2 = Mp[i*NJC+2];
    float M  = fmaxf(fmaxf(m0, m1), m2);
    float w0 = __expf(m0 - M), w1 = __expf(m1 - M), w2 = __expf(m2 - M);
    float den = w0*Lp[i*NJC+0] + w1*Lp[i*NJC+1] + w2*Lp[i*NJC+2];
    float inv = 1.0f / den;

    float num = w0 * hp[((size_t)0*NN + i)*CC + t]
              + w1 * hp[((size_t)1*NN + i)*CC + t]
              + w2 * hp[((size_t)2*NN + i)*CC + t];
    float v = num * inv;
    out[i*CC + t] = (v > 0.f) ? v : (__expf(v) - 1.0f);
}

extern "C" void kernel_launch(void* const* d_in, const int* in_sizes, int n_in,
                              void* d_out, int out_size, void* d_ws, size_t ws_size,
                              hipStream_t stream) {
    const float* features = (const float*)d_in[0];
    const float* coords   = (const float*)d_in[1];
    // d_in[2] = adj, unused by forward
    const float* FC       = (const float*)d_in[3];
    const float* fc_w     = (const float*)d_in[4];
    const float* fc_b     = (const float*)d_in[5];
    const float* sc_w     = (const float*)d_in[6];
    const float* sc_b     = (const float*)d_in[7];
    const float* lin_w    = (const float*)d_in[8];
    const float* lin_b    = (const float*)d_in[9];
    float* out = (float*)d_out;

    float* f  = (float*)d_ws;              // N*C
    float* g  = f  + NN*CC;                // C*N
    float* D0 = g  + CC*NN;                // N
    float* D1 = D0 + NN;                   // N
    float* Mp = D1 + NN;                   // N*NJC
    float* Lp = Mp + NN*NJC;               // N*NJC
    float* hp = Lp + NN*NJC;               // NJC*N*C
    float4* ut4;
    {
        size_t off = (size_t)((char*)(hp + (size_t)NJC*NN*CC) - (char*)d_ws);
        off = (off + 15) & ~(size_t)15;
        ut4 = (float4*)((char*)d_ws + off); // (N/3)*C float4, 16B-aligned
    }

    k_prep<<<NN/TI, 768, 0, stream>>>(features, FC, fc_w, fc_b, lin_w, f, g, D0, D1, ut4);
    k_attn<<<(NN/TI)*NJC, 256, 0, stream>>>(f, g, ut4, D0, D1, coords, sc_w, sc_b,
                                            lin_w, lin_b, hp, Mp, Lp);
    k_comb<<<NN, 256, 0, stream>>>(hp, Mp, Lp, out);
}

// Round 9
// 115.888 us; speedup vs baseline: 1.0445x; 1.0445x over previous
//
#include <hip/hip_runtime.h>
#include <math.h>

#define NN 768
#define CC 256
#define TI 3     // rows per block (both kernels)
#define JC 256   // j columns per k_attn block
#define NJC 3    // j chunks: 3 * 256 = 768

__device__ __forceinline__ float leaky(float x) { return x >= 0.0f ? x : 0.2f * x; }

__device__ __forceinline__ float waveMax(float v) {
    #pragma unroll
    for (int o = 32; o > 0; o >>= 1) v = fmaxf(v, __shfl_xor(v, o, 64));
    return v;
}
__device__ __forceinline__ float waveSum(float v) {
    #pragma unroll
    for (int o = 32; o > 0; o >>= 1) v += __shfl_xor(v, o, 64);
    return v;
}

// Kernel 1 (unchanged): f = features @ FC; g[c][j] = w1*f[j][c]+b;
// D0/D1 = per-row linear-term dots; ut4[triple][c] = {w0*f_r0[c], w0*f_r1[c],
// w0*f_r2[c], 0.4*lin_w[c]}.
__global__ __launch_bounds__(768) void k_prep(
    const float* __restrict__ features,
    const float* __restrict__ FC,
    const float* __restrict__ fc_w,
    const float* __restrict__ fc_b,
    const float* __restrict__ lin_w,
    float* __restrict__ f,
    float* __restrict__ g,
    float* __restrict__ D0,
    float* __restrict__ D1,
    float4* __restrict__ ut4)
{
    __shared__ float sA[TI * CC];
    __shared__ float sF[TI * CC];
    __shared__ float sredD[12], sredW[12];

    const int t  = threadIdx.x;
    const int r  = t >> 8;
    const int c  = t & 255;
    const int i0 = blockIdx.x * TI;

    sA[r * CC + c] = features[(i0 + r) * CC + c];
    __syncthreads();

    float a = 0.f;
    const float* fcp = FC + c;
    const float* ap  = sA + r * CC;
    #pragma unroll 8
    for (int k = 0; k < CC; ++k)
        a = fmaf(ap[k], fcp[k * CC], a);

    const float w1 = fc_w[1], b = fc_b[0];
    f[(i0 + r) * CC + c] = a;
    g[c * NN + i0 + r]   = fmaf(w1, a, b);
    sF[r * CC + c] = a;

    const float lw = lin_w[c];
    float dv = waveSum(lw * a);
    float wv = waveSum(lw);
    const int wid = t >> 6;
    if ((t & 63) == 0) { sredD[wid] = dv; sredW[wid] = wv; }
    __syncthreads();
    if (t < TI) {
        float D = sredD[t*4] + sredD[t*4+1] + sredD[t*4+2] + sredD[t*4+3];
        float W = sredW[t*4] + sredW[t*4+1] + sredW[t*4+2] + sredW[t*4+3];
        D0[i0 + t] = fc_w[0] * D;
        D1[i0 + t] = fmaf(w1, D, b * W);
    }
    if (t < CC) {
        const float w0 = fc_w[0];
        ut4[blockIdx.x * CC + t] = make_float4(w0 * sF[t],
                                               w0 * sF[CC + t],
                                               w0 * sF[2*CC + t],
                                               0.4f * lin_w[t]);
    }
}

// Kernel 2: 768 blocks x 256 threads, block = (row-triple it, j-chunk jc).
// Phase 1 NEW: lane owns a j-QUAD (float4 g loads -> 4x bytes in flight,
// latency-bound -> BW-bound), wave owns a 64-c slice; cross-wave c-reduction
// through LDS. Tail/softmax/phase-3 identical to round 7.
__global__ __launch_bounds__(256) void k_attn(
    const float* __restrict__ f,      // [N][C]
    const float* __restrict__ g,      // [C][N]
    const float4* __restrict__ ut4,   // [N/3][C]
    const float* __restrict__ D0,     // [N]
    const float* __restrict__ D1,     // [N]
    const float* __restrict__ coords, // [N][3]
    const float* __restrict__ sc_w,
    const float* __restrict__ sc_b,
    const float* __restrict__ lin_w,  // [C+3]
    const float* __restrict__ lin_b,
    float* __restrict__ hp,           // [NJC][N][C] partial sums
    float* __restrict__ Mp,           // [N][NJC] partial max
    float* __restrict__ Lp)           // [N][NJC] partial expsum
{
    __shared__ float  spart[4][TI][JC]; // 12 KB: per-c-slice score partials
    __shared__ float4 pp[JC];           // 4 KB: {e0,e1,e2,-} per block-local j
    __shared__ float  hpart[4][TI][CC]; // 12 KB: per-wave h partials
    __shared__ float4 sredm4[4];
    __shared__ float4 sreds4[4];

    const int t    = threadIdx.x;
    const int it   = blockIdx.x & 255;  // row-triple
    const int jc   = blockIdx.x >> 8;   // j-chunk 0..2
    const int i0   = it * TI;
    const int jb   = jc * JC;
    const int j    = jb + t;
    const int w    = t >> 6;
    const int lane = t & 63;

    // ---- Phase 1: acc[rr] over c-slice [64w,64w+64) for j-quad jb+4*lane ----
    float4 a0 = make_float4(0.f,0.f,0.f,0.f);
    float4 a1 = a0, a2 = a0;
    // g element index (c*NN + jb + 4*lane)/4 = c*192 + jb/4 + lane
    const float4* gq = (const float4*)g + (size_t)(w << 6) * (NN/4) + (jb >> 2) + lane;
    const float4* up = ut4 + (size_t)it * CC + (w << 6);   // wave-uniform
    #pragma unroll 8
    for (int cc = 0; cc < 64; ++cc) {
        float4 gv = gq[cc * (NN/4)];   // coalesced 1KB/wave
        float4 u  = up[cc];            // wave-uniform, L1
        a0.x = fmaf(u.w, fabsf(u.x + gv.x), a0.x);
        a0.y = fmaf(u.w, fabsf(u.x + gv.y), a0.y);
        a0.z = fmaf(u.w, fabsf(u.x + gv.z), a0.z);
        a0.w = fmaf(u.w, fabsf(u.x + gv.w), a0.w);
        a1.x = fmaf(u.w, fabsf(u.y + gv.x), a1.x);
        a1.y = fmaf(u.w, fabsf(u.y + gv.y), a1.y);
        a1.z = fmaf(u.w, fabsf(u.y + gv.z), a1.z);
        a1.w = fmaf(u.w, fabsf(u.y + gv.w), a1.w);
        a2.x = fmaf(u.w, fabsf(u.z + gv.x), a2.x);
        a2.y = fmaf(u.w, fabsf(u.z + gv.y), a2.y);
        a2.z = fmaf(u.w, fabsf(u.z + gv.z), a2.z);
        a2.w = fmaf(u.w, fabsf(u.z + gv.w), a2.w);
    }
    {
        const int jl4 = 4 * lane;
        spart[w][0][jl4+0] = a0.x; spart[w][0][jl4+1] = a0.y;
        spart[w][0][jl4+2] = a0.z; spart[w][0][jl4+3] = a0.w;
        spart[w][1][jl4+0] = a1.x; spart[w][1][jl4+1] = a1.y;
        spart[w][1][jl4+2] = a1.z; spart[w][1][jl4+3] = a1.w;
        spart[w][2][jl4+0] = a2.x; spart[w][2][jl4+1] = a2.y;
        spart[w][2][jl4+2] = a2.z; spart[w][2][jl4+3] = a2.w;
    }
    __syncthreads();

    // ---- Tail: thread t owns j = jb + t (round-7 structure) ----
    float accs[3];
    #pragma unroll
    for (int rr = 0; rr < TI; ++rr)
        accs[rr] = spart[0][rr][t] + spart[1][rr][t]
                 + spart[2][rr][t] + spart[3][rr][t];

    const float sw0 = sc_w[0], sw1 = sc_w[1], sb = sc_b[0], lb = lin_b[0];
    const float lw30 = lin_w[CC], lw31 = lin_w[CC+1], lw32 = lin_w[CC+2];
    const float cj0 = fmaf(sw1, coords[j*3+0], sb);
    const float cj1 = fmaf(sw1, coords[j*3+1], sb);
    const float cj2 = fmaf(sw1, coords[j*3+2], sb);
    const float d1  = D1[j];
    float scv[3];
    #pragma unroll
    for (int rr = 0; rr < TI; ++rr) {
        const int i = i0 + rr;
        float sd = lw30 * leaky(fmaf(sw0, coords[i*3+0], cj0))
                 + lw31 * leaky(fmaf(sw0, coords[i*3+1], cj1))
                 + lw32 * leaky(fmaf(sw0, coords[i*3+2], cj2));
        scv[rr] = leaky(accs[rr] + sd + 0.6f * (D0[i] + d1) + lb);
    }

    // ---- Phase 2: partial softmax over this block's 256 j ----
    {
        float v0 = waveMax(scv[0]);
        float v1 = waveMax(scv[1]);
        float v2 = waveMax(scv[2]);
        if (lane == 0) sredm4[w] = make_float4(v0, v1, v2, 0.f);
    }
    __syncthreads();
    float m[TI];
    {
        float4 x0 = sredm4[0], x1 = sredm4[1], x2 = sredm4[2], x3 = sredm4[3];
        m[0] = fmaxf(fmaxf(x0.x, x1.x), fmaxf(x2.x, x3.x));
        m[1] = fmaxf(fmaxf(x0.y, x1.y), fmaxf(x2.y, x3.y));
        m[2] = fmaxf(fmaxf(x0.z, x1.z), fmaxf(x2.z, x3.z));
    }
    float e0 = __expf(scv[0] - m[0]);
    float e1 = __expf(scv[1] - m[1]);
    float e2 = __expf(scv[2] - m[2]);
    pp[t] = make_float4(e0, e1, e2, 0.f);
    {
        float v0 = waveSum(e0);
        float v1 = waveSum(e1);
        float v2 = waveSum(e2);
        if (lane == 0) sreds4[w] = make_float4(v0, v1, v2, 0.f);
    }
    __syncthreads();   // publishes pp + sreds4
    if (t < TI) {
        float4 s0 = sreds4[0], s1 = sreds4[1], s2 = sreds4[2], s3 = sreds4[3];
        float l = (t == 0) ? (s0.x + s1.x + s2.x + s3.x)
                : (t == 1) ? (s0.y + s1.y + s2.y + s3.y)
                           : (s0.z + s1.z + s2.z + s3.z);
        float mm = (t == 0) ? m[0] : (t == 1) ? m[1] : m[2];
        Mp[(i0 + t) * NJC + jc] = mm;
        Lp[(i0 + t) * NJC + jc] = l;
    }

    // ---- Phase 3: wave w owns j-slice [64w,64w+64); lane owns 4 channels ----
    float4 h0 = make_float4(0.f,0.f,0.f,0.f);
    float4 h1 = h0, h2 = h0;
    const float4* f4 = (const float4*)f;   // [N][64] float4
    const int jsl = w * 64;
    #pragma unroll 4
    for (int jx = 0; jx < 64; ++jx) {
        const int jl = jsl + jx;
        float4 fv = f4[(size_t)(jb + jl) * 64 + lane];  // coalesced 1KB/wave
        float4 e  = pp[jl];                              // ds_read_b128 broadcast
        h0.x = fmaf(e.x, fv.x, h0.x); h0.y = fmaf(e.x, fv.y, h0.y);
        h0.z = fmaf(e.x, fv.z, h0.z); h0.w = fmaf(e.x, fv.w, h0.w);
        h1.x = fmaf(e.y, fv.x, h1.x); h1.y = fmaf(e.y, fv.y, h1.y);
        h1.z = fmaf(e.y, fv.z, h1.z); h1.w = fmaf(e.y, fv.w, h1.w);
        h2.x = fmaf(e.z, fv.x, h2.x); h2.y = fmaf(e.z, fv.y, h2.y);
        h2.z = fmaf(e.z, fv.z, h2.z); h2.w = fmaf(e.z, fv.w, h2.w);
    }
    *(float4*)&hpart[w][0][4*lane] = h0;
    *(float4*)&hpart[w][1][4*lane] = h1;
    *(float4*)&hpart[w][2][4*lane] = h2;
    __syncthreads();

    // ---- Reduce the 4 wave-partials per row; store hp ----
    #pragma unroll
    for (int r = 0; r < TI; ++r) {
        float h = hpart[0][r][t] + hpart[1][r][t] + hpart[2][r][t] + hpart[3][r][t];
        hp[((size_t)jc * NN + i0 + r) * CC + t] = h;
    }
}

// Kernel 3: combine the 3 j-chunk partials per row, normalize, elu.
__global__ __launch_bounds__(256) void k_comb(
    const float* __restrict__ hp,
    const float* __restrict__ Mp,
    const float* __restrict__ Lp,
    float* __restrict__ out)
{
    const int t = threadIdx.x;
    const int i = blockIdx.x;

    float m0 = Mp[i*NJC+0], m1 = Mp[i*NJC+1], m2 = Mp[i*NJC+2];
    float M  = fmaxf(fmaxf(m0, m1), m2);
    float w0 = __expf(m0 - M), w1 = __expf(m1 - M), w2 = __expf(m2 - M);
    float den = w0*Lp[i*NJC+0] + w1*Lp[i*NJC+1] + w2*Lp[i*NJC+2];
    float inv = 1.0f / den;

    float num = w0 * hp[((size_t)0*NN + i)*CC + t]
              + w1 * hp[((size_t)1*NN + i)*CC + t]
              + w2 * hp[((size_t)2*NN + i)*CC + t];
    float v = num * inv;
    out[i*CC + t] = (v > 0.f) ? v : (__expf(v) - 1.0f);
}

extern "C" void kernel_launch(void* const* d_in, const int* in_sizes, int n_in,
                              void* d_out, int out_size, void* d_ws, size_t ws_size,
                              hipStream_t stream) {
    const float* features = (const float*)d_in[0];
    const float* coords   = (const float*)d_in[1];
    // d_in[2] = adj, unused by forward
    const float* FC       = (const float*)d_in[3];
    const float* fc_w     = (const float*)d_in[4];
    const float* fc_b     = (const float*)d_in[5];
    const float* sc_w     = (const float*)d_in[6];
    const float* sc_b     = (const float*)d_in[7];
    const float* lin_w    = (const float*)d_in[8];
    const float* lin_b    = (const float*)d_in[9];
    float* out = (float*)d_out;

    float* f  = (float*)d_ws;              // N*C
    float* g  = f  + NN*CC;                // C*N
    float* D0 = g  + CC*NN;                // N
    float* D1 = D0 + NN;                   // N
    float* Mp = D1 + NN;                   // N*NJC
    float* Lp = Mp + NN*NJC;               // N*NJC
    float* hp = Lp + NN*NJC;               // NJC*N*C
    float4* ut4;
    {
        size_t off = (size_t)((char*)(hp + (size_t)NJC*NN*CC) - (char*)d_ws);
        off = (off + 15) & ~(size_t)15;
        ut4 = (float4*)((char*)d_ws + off); // (N/3)*C float4, 16B-aligned
    }

    k_prep<<<NN/TI, 768, 0, stream>>>(features, FC, fc_w, fc_b, lin_w, f, g, D0, D1, ut4);
    k_attn<<<(NN/TI)*NJC, 256, 0, stream>>>(f, g, ut4, D0, D1, coords, sc_w, sc_b,
                                            lin_w, lin_b, hp, Mp, Lp);
    k_comb<<<NN, 256, 0, stream>>>(hp, Mp, Lp, out);
}

// Round 10
// 112.413 us; speedup vs baseline: 1.0768x; 1.0309x over previous
//
#include <hip/hip_runtime.h>
#include <math.h>

#define NN 768
#define CC 256
#define TI 3     // rows per block (both kernels)
#define JC 256   // j columns per k_attn block
#define NJC 3    // j chunks: 3 * 256 = 768

__device__ __forceinline__ float leaky(float x) { return x >= 0.0f ? x : 0.2f * x; }

__device__ __forceinline__ float waveMax(float v) {
    #pragma unroll
    for (int o = 32; o > 0; o >>= 1) v = fmaxf(v, __shfl_xor(v, o, 64));
    return v;
}
__device__ __forceinline__ float waveSum(float v) {
    #pragma unroll
    for (int o = 32; o > 0; o >>= 1) v += __shfl_xor(v, o, 64);
    return v;
}

// Kernel 1 (unchanged): f = features @ FC; g[c][j] = w1*f[j][c]+b;
// D0/D1 = per-row linear-term dots; ut4[triple][c] = {w0*f_r0[c], w0*f_r1[c],
// w0*f_r2[c], 0.4*lin_w[c]}.
__global__ __launch_bounds__(768) void k_prep(
    const float* __restrict__ features,
    const float* __restrict__ FC,
    const float* __restrict__ fc_w,
    const float* __restrict__ fc_b,
    const float* __restrict__ lin_w,
    float* __restrict__ f,
    float* __restrict__ g,
    float* __restrict__ D0,
    float* __restrict__ D1,
    float4* __restrict__ ut4)
{
    __shared__ float sA[TI * CC];
    __shared__ float sF[TI * CC];
    __shared__ float sredD[12], sredW[12];

    const int t  = threadIdx.x;
    const int r  = t >> 8;
    const int c  = t & 255;
    const int i0 = blockIdx.x * TI;

    sA[r * CC + c] = features[(i0 + r) * CC + c];
    __syncthreads();

    float a = 0.f;
    const float* fcp = FC + c;
    const float* ap  = sA + r * CC;
    #pragma unroll 8
    for (int k = 0; k < CC; ++k)
        a = fmaf(ap[k], fcp[k * CC], a);

    const float w1 = fc_w[1], b = fc_b[0];
    f[(i0 + r) * CC + c] = a;
    g[c * NN + i0 + r]   = fmaf(w1, a, b);
    sF[r * CC + c] = a;

    const float lw = lin_w[c];
    float dv = waveSum(lw * a);
    float wv = waveSum(lw);
    const int wid = t >> 6;
    if ((t & 63) == 0) { sredD[wid] = dv; sredW[wid] = wv; }
    __syncthreads();
    if (t < TI) {
        float D = sredD[t*4] + sredD[t*4+1] + sredD[t*4+2] + sredD[t*4+3];
        float W = sredW[t*4] + sredW[t*4+1] + sredW[t*4+2] + sredW[t*4+3];
        D0[i0 + t] = fc_w[0] * D;
        D1[i0 + t] = fmaf(w1, D, b * W);
    }
    if (t < CC) {
        const float w0 = fc_w[0];
        ut4[blockIdx.x * CC + t] = make_float4(w0 * sF[t],
                                               w0 * sF[CC + t],
                                               w0 * sF[2*CC + t],
                                               0.4f * lin_w[t]);
    }
}

// Kernel 2: 768 blocks x 256 threads, block = (row-triple it, j-chunk jc).
// Phase 1: lane owns a j-quad (float4 g loads, 96 KB in flight); wave owns a
// 64-c slice; u comes from a 4 KB LDS stage via ds_read_b128 BROADCAST —
// round 9's wave-uniform vector u-load returned a replicated 1 KB/wave
// through the TCP, a third of the VMEM bill.
__global__ __launch_bounds__(256) void k_attn(
    const float* __restrict__ f,      // [N][C]
    const float* __restrict__ g,      // [C][N]
    const float4* __restrict__ ut4,   // [N/3][C]
    const float* __restrict__ D0,     // [N]
    const float* __restrict__ D1,     // [N]
    const float* __restrict__ coords, // [N][3]
    const float* __restrict__ sc_w,
    const float* __restrict__ sc_b,
    const float* __restrict__ lin_w,  // [C+3]
    const float* __restrict__ lin_b,
    float* __restrict__ hp,           // [NJC][N][C] partial sums
    float* __restrict__ Mp,           // [N][NJC] partial max
    float* __restrict__ Lp)           // [N][NJC] partial expsum
{
    __shared__ float4 su4[CC];          // 4 KB: staged u for this row-triple
    __shared__ float  spart[4][TI][JC]; // 12 KB: per-c-slice score partials
    __shared__ float4 pp[JC];           // 4 KB: {e0,e1,e2,-} per block-local j
    __shared__ float  hpart[4][TI][CC]; // 12 KB: per-wave h partials
    __shared__ float4 sredm4[4];
    __shared__ float4 sreds4[4];

    const int t    = threadIdx.x;
    const int it   = blockIdx.x & 255;  // row-triple
    const int jc   = blockIdx.x >> 8;   // j-chunk 0..2
    const int i0   = it * TI;
    const int jb   = jc * JC;
    const int j    = jb + t;
    const int w    = t >> 6;
    const int lane = t & 63;

    // stage u into LDS (one coalesced 4 KB read per block)
    su4[t] = ut4[(size_t)it * CC + t];
    __syncthreads();

    // ---- Phase 1: acc[rr] over c-slice [64w,64w+64) for j-quad jb+4*lane ----
    float4 a0 = make_float4(0.f,0.f,0.f,0.f);
    float4 a1 = a0, a2 = a0;
    const float4* gq = (const float4*)g + (size_t)(w << 6) * (NN/4) + (jb >> 2) + lane;
    const float4* su = su4 + (w << 6);
    #pragma unroll 8
    for (int cc = 0; cc < 64; ++cc) {
        float4 gv = gq[cc * (NN/4)];   // coalesced 1KB/wave, L2
        float4 u  = su[cc];            // ds_read_b128 broadcast (conflict-free)
        a0.x = fmaf(u.w, fabsf(u.x + gv.x), a0.x);
        a0.y = fmaf(u.w, fabsf(u.x + gv.y), a0.y);
        a0.z = fmaf(u.w, fabsf(u.x + gv.z), a0.z);
        a0.w = fmaf(u.w, fabsf(u.x + gv.w), a0.w);
        a1.x = fmaf(u.w, fabsf(u.y + gv.x), a1.x);
        a1.y = fmaf(u.w, fabsf(u.y + gv.y), a1.y);
        a1.z = fmaf(u.w, fabsf(u.y + gv.z), a1.z);
        a1.w = fmaf(u.w, fabsf(u.y + gv.w), a1.w);
        a2.x = fmaf(u.w, fabsf(u.z + gv.x), a2.x);
        a2.y = fmaf(u.w, fabsf(u.z + gv.y), a2.y);
        a2.z = fmaf(u.w, fabsf(u.z + gv.z), a2.z);
        a2.w = fmaf(u.w, fabsf(u.z + gv.w), a2.w);
    }
    *(float4*)&spart[w][0][4*lane] = a0;
    *(float4*)&spart[w][1][4*lane] = a1;
    *(float4*)&spart[w][2][4*lane] = a2;
    __syncthreads();

    // ---- Tail: thread t owns j = jb + t ----
    float accs[3];
    #pragma unroll
    for (int rr = 0; rr < TI; ++rr)
        accs[rr] = spart[0][rr][t] + spart[1][rr][t]
                 + spart[2][rr][t] + spart[3][rr][t];

    const float sw0 = sc_w[0], sw1 = sc_w[1], sb = sc_b[0], lb = lin_b[0];
    const float lw30 = lin_w[CC], lw31 = lin_w[CC+1], lw32 = lin_w[CC+2];
    const float cj0 = fmaf(sw1, coords[j*3+0], sb);
    const float cj1 = fmaf(sw1, coords[j*3+1], sb);
    const float cj2 = fmaf(sw1, coords[j*3+2], sb);
    const float d1  = D1[j];
    float scv[3];
    #pragma unroll
    for (int rr = 0; rr < TI; ++rr) {
        const int i = i0 + rr;
        float sd = lw30 * leaky(fmaf(sw0, coords[i*3+0], cj0))
                 + lw31 * leaky(fmaf(sw0, coords[i*3+1], cj1))
                 + lw32 * leaky(fmaf(sw0, coords[i*3+2], cj2));
        scv[rr] = leaky(accs[rr] + sd + 0.6f * (D0[i] + d1) + lb);
    }

    // ---- Phase 2: partial softmax over this block's 256 j ----
    {
        float v0 = waveMax(scv[0]);
        float v1 = waveMax(scv[1]);
        float v2 = waveMax(scv[2]);
        if (lane == 0) sredm4[w] = make_float4(v0, v1, v2, 0.f);
    }
    __syncthreads();
    float m[TI];
    {
        float4 x0 = sredm4[0], x1 = sredm4[1], x2 = sredm4[2], x3 = sredm4[3];
        m[0] = fmaxf(fmaxf(x0.x, x1.x), fmaxf(x2.x, x3.x));
        m[1] = fmaxf(fmaxf(x0.y, x1.y), fmaxf(x2.y, x3.y));
        m[2] = fmaxf(fmaxf(x0.z, x1.z), fmaxf(x2.z, x3.z));
    }
    float e0 = __expf(scv[0] - m[0]);
    float e1 = __expf(scv[1] - m[1]);
    float e2 = __expf(scv[2] - m[2]);
    pp[t] = make_float4(e0, e1, e2, 0.f);
    {
        float v0 = waveSum(e0);
        float v1 = waveSum(e1);
        float v2 = waveSum(e2);
        if (lane == 0) sreds4[w] = make_float4(v0, v1, v2, 0.f);
    }
    __syncthreads();   // publishes pp + sreds4
    if (t < TI) {
        float4 s0 = sreds4[0], s1 = sreds4[1], s2 = sreds4[2], s3 = sreds4[3];
        float l = (t == 0) ? (s0.x + s1.x + s2.x + s3.x)
                : (t == 1) ? (s0.y + s1.y + s2.y + s3.y)
                           : (s0.z + s1.z + s2.z + s3.z);
        float mm = (t == 0) ? m[0] : (t == 1) ? m[1] : m[2];
        Mp[(i0 + t) * NJC + jc] = mm;
        Lp[(i0 + t) * NJC + jc] = l;
    }

    // ---- Phase 3: wave w owns j-slice [64w,64w+64); lane owns 4 channels ----
    float4 h0 = make_float4(0.f,0.f,0.f,0.f);
    float4 h1 = h0, h2 = h0;
    const float4* f4 = (const float4*)f;   // [N][64] float4
    const int jsl = w * 64;
    #pragma unroll 4
    for (int jx = 0; jx < 64; ++jx) {
        const int jl = jsl + jx;
        float4 fv = f4[(size_t)(jb + jl) * 64 + lane];  // coalesced 1KB/wave
        float4 e  = pp[jl];                              // ds_read_b128 broadcast
        h0.x = fmaf(e.x, fv.x, h0.x); h0.y = fmaf(e.x, fv.y, h0.y);
        h0.z = fmaf(e.x, fv.z, h0.z); h0.w = fmaf(e.x, fv.w, h0.w);
        h1.x = fmaf(e.y, fv.x, h1.x); h1.y = fmaf(e.y, fv.y, h1.y);
        h1.z = fmaf(e.y, fv.z, h1.z); h1.w = fmaf(e.y, fv.w, h1.w);
        h2.x = fmaf(e.z, fv.x, h2.x); h2.y = fmaf(e.z, fv.y, h2.y);
        h2.z = fmaf(e.z, fv.z, h2.z); h2.w = fmaf(e.z, fv.w, h2.w);
    }
    *(float4*)&hpart[w][0][4*lane] = h0;
    *(float4*)&hpart[w][1][4*lane] = h1;
    *(float4*)&hpart[w][2][4*lane] = h2;
    __syncthreads();

    // ---- Reduce the 4 wave-partials per row; store hp ----
    #pragma unroll
    for (int r = 0; r < TI; ++r) {
        float h = hpart[0][r][t] + hpart[1][r][t] + hpart[2][r][t] + hpart[3][r][t];
        hp[((size_t)jc * NN + i0 + r) * CC + t] = h;
    }
}

// Kernel 3: combine the 3 j-chunk partials per row, normalize, elu.
__global__ __launch_bounds__(256) void k_comb(
    const float* __restrict__ hp,
    const float* __restrict__ Mp,
    const float* __restrict__ Lp,
    float* __restrict__ out)
{
    const int t = threadIdx.x;
    const int i = blockIdx.x;

    float m0 = Mp[i*NJC+0], m1 = Mp[i*NJC+1], m2 = Mp[i*NJC+2];
    float M  = fmaxf(fmaxf(m0, m1), m2);
    float w0 = __expf(m0 - M), w1 = __expf(m1 - M), w2 = __expf(m2 - M);
    float den = w0*Lp[i*NJC+0] + w1*Lp[i*NJC+1] + w2*Lp[i*NJC+2];
    float inv = 1.0f / den;

    float num = w0 * hp[((size_t)0*NN + i)*CC + t]
              + w1 * hp[((size_t)1*NN + i)*CC + t]
              + w2 * hp[((size_t)2*NN + i)*CC + t];
    float v = num * inv;
    out[i*CC + t] = (v > 0.f) ? v : (__expf(v) - 1.0f);
}

extern "C" void kernel_launch(void* const* d_in, const int* in_sizes, int n_in,
                              void* d_out, int out_size, void* d_ws, size_t ws_size,
                              hipStream_t stream) {
    const float* features = (const float*)d_in[0];
    const float* coords   = (const float*)d_in[1];
    // d_in[2] = adj, unused by forward
    const float* FC       = (const float*)d_in[3];
    const float* fc_w     = (const float*)d_in[4];
    const float* fc_b     = (const float*)d_in[5];
    const float* sc_w     = (const float*)d_in[6];
    const float* sc_b     = (const float*)d_in[7];
    const float* lin_w    = (const float*)d_in[8];
    const float* lin_b    = (const float*)d_in[9];
    float* out = (float*)d_out;

    float* f  = (float*)d_ws;              // N*C
    float* g  = f  + NN*CC;                // C*N
    float* D0 = g  + CC*NN;                // N
    float* D1 = D0 + NN;                   // N
    float* Mp = D1 + NN;                   // N*NJC
    float* Lp = Mp + NN*NJC;               // N*NJC
    float* hp = Lp + NN*NJC;               // NJC*N*C
    float4* ut4;
    {
        size_t off = (size_t)((char*)(hp + (size_t)NJC*NN*CC) - (char*)d_ws);
        off = (off + 15) & ~(size_t)15;
        ut4 = (float4*)((char*)d_ws + off); // (N/3)*C float4, 16B-aligned
    }

    k_prep<<<NN/TI, 768, 0, stream>>>(features, FC, fc_w, fc_b, lin_w, f, g, D0, D1, ut4);
    k_attn<<<(NN/TI)*NJC, 256, 0, stream>>>(f, g, ut4, D0, D1, coords, sc_w, sc_b,
                                            lin_w, lin_b, hp, Mp, Lp);
    k_comb<<<NN, 256, 0, stream>>>(hp, Mp, Lp, out);
}